// Round 2
// baseline (124.436 us; speedup 1.0000x reference)
//
#include <hip/hip_runtime.h>
#include <hip/hip_fp16.h>

#define ACN_EPS   0.001f
#define ACN_LOG2E 1.4426950408889634f
#define ACN_LN2   0.6931471805599453f
#define TBL_N     2048
#define TBL_LO    -8.0f
#define TBL_SCALE 128.0f      // TBL_N / (HI-LO) = 2048/16
#define TBL_OFF   1024.0f     // -TBL_LO * TBL_SCALE
#define TBL_MAX_T 2047.999f

typedef float v4f  __attribute__((ext_vector_type(4)));
typedef unsigned int u32;
typedef u32 v4u __attribute__((ext_vector_type(4)));

// ---------------------------------------------------------------------------
// Per-element interpolation: fma/med3/cvt -> one ds_read_b32 gather ->
// 2x cvt_f32_f16 -> interp fma. Memory-bound.
// ---------------------------------------------------------------------------
__device__ __forceinline__ float acn_interp(const u32* tbl, float xx) {
    float t  = fmaf(xx, TBL_SCALE, TBL_OFF);
    t        = __builtin_amdgcn_fmed3f(t, 0.0f, TBL_MAX_T);
    int   ii = (int)t;
    float f  = t - (float)ii;
    u32 u = tbl[ii];
    __half2 hv = *(const __half2*)&u;
    return fmaf(__high2float(hv), f, __low2float(hv));
}

__device__ __forceinline__ v4f acn_interp4(const u32* tbl, v4f xv) {
    v4f r;
    r.x = acn_interp(tbl, xv.x);
    r.y = acn_interp(tbl, xv.y);
    r.z = acn_interp(tbl, xv.z);
    r.w = acn_interp(tbl, xv.w);
    return r;
}

// ---------------------------------------------------------------------------
// Fused kernel, depth-8 pipelined: issue 8 v4f NT loads per thread (128 KB in
// flight per CU) BEFORE the per-block LDS table build so HBM stays saturated
// during the ~2 us VALU/transcendental burst; then stream 16 v4f/thread
// through a depth-8 software pipeline with statically-named buffers.
// ---------------------------------------------------------------------------
__global__ __launch_bounds__(256, 4) void acn_fused(
        const v4f* __restrict__ x,
        v4f* __restrict__ out,
        const float* __restrict__ mean,
        const float* __restrict__ variance,
        const float* __restrict__ prior,
        int n4) {
    __shared__ u32 tbl[TBL_N];

    const int Tn  = gridDim.x * blockDim.x;   // 1024*256 = 262144
    const int idx = blockIdx.x * blockDim.x + threadIdx.x;
    const bool fast = (n4 == 16 * Tn);

    // Depth-8 prefetch: ~32 MB chip-wide in flight while the table builds.
    v4f b0, b1, b2, b3, b4, b5, b6, b7;
    if (fast) {
        b0 = __builtin_nontemporal_load(&x[idx]);
        b1 = __builtin_nontemporal_load(&x[idx + 1 * Tn]);
        b2 = __builtin_nontemporal_load(&x[idx + 2 * Tn]);
        b3 = __builtin_nontemporal_load(&x[idx + 3 * Tn]);
        b4 = __builtin_nontemporal_load(&x[idx + 4 * Tn]);
        b5 = __builtin_nontemporal_load(&x[idx + 5 * Tn]);
        b6 = __builtin_nontemporal_load(&x[idx + 6 * Tn]);
        b7 = __builtin_nontemporal_load(&x[idx + 7 * Tn]);
    }

    // ---- table build (all-intrinsic math; uniform params -> s_loads) ----
    {
        float e[8];
        float mx = -1e30f;
#pragma unroll
        for (int k = 0; k < 8; ++k) { e[k] = prior[k]; mx = fmaxf(mx, e[k]); }
        float sum = 0.0f;
#pragma unroll
        for (int k = 0; k < 8; ++k) {
            e[k] = __builtin_amdgcn_exp2f((e[k] - mx) * ACN_LOG2E);
            sum += e[k];
        }
        float rs = __builtin_amdgcn_rcpf(sum);

        const float h  = 1.0f / TBL_SCALE;
        const float x0 = TBL_LO + (float)(threadIdx.x * 8) * h;

        float denom[9], S[9];
#pragma unroll
        for (int j = 0; j < 9; ++j) { denom[j] = 0.0f; S[j] = 0.0f; }

#pragma unroll
        for (int k = 0; k < 8; ++k) {
            float pk = e[k] * rs;                                 // softmax(prior)
            // softplus(v) = ln(1 + e^v) = log2(1 + 2^(v*log2e)) * ln2
            float v  = __builtin_amdgcn_logf(1.0f +
                         __builtin_amdgcn_exp2f(variance[k] * ACN_LOG2E)) * ACN_LN2;
            float ve = v + ACN_EPS;
            float rv  = __builtin_amdgcn_rcpf(v);
            float rve = __builtin_amdgcn_rcpf(ve);
            float mu  = mean[k];
            float s1  = -0.5f * ACN_LOG2E * rv * rv;
            float s2  = -0.5f * ACN_LOG2E * rve * rve;
            float lp  = __builtin_amdgcn_logf(pk);
            float lw  = lp - 0.5f * __builtin_amdgcn_logf(pk + ACN_EPS)
                           - 0.5f * __builtin_amdgcn_logf(ve);
#pragma unroll
            for (int j = 0; j < 9; ++j) {
                float d  = x0 + (float)j * h - mu;
                float d2 = d * d;
                denom[j] += __builtin_amdgcn_exp2f(fmaf(s1, d2, lp));
                S[j] = fmaf(__builtin_amdgcn_exp2f(fmaf(s2, d2, lw)), d, S[j]);
            }
        }

        u32 packed[8];
        float y_prev = S[0] * __builtin_amdgcn_rcpf(denom[0] + ACN_EPS);
#pragma unroll
        for (int j = 0; j < 8; ++j) {
            float y_next = S[j + 1] * __builtin_amdgcn_rcpf(denom[j + 1] + ACN_EPS);
            __half2 hv = __halves2half2(__float2half(y_prev),
                                        __float2half(y_next - y_prev));
            packed[j] = *(const u32*)&hv;
            y_prev = y_next;
        }
        // 8 consecutive dwords per thread -> two b128 writes (one-time cost).
        *(v4u*)&tbl[threadIdx.x * 8]     = *(v4u*)&packed[0];
        *(v4u*)&tbl[threadIdx.x * 8 + 4] = *(v4u*)&packed[4];
    }
    __syncthreads();

    // ---- streaming main loop: depth-8 software pipeline, static regs ----
    if (fast) {
#define ACN_STEP(c, buf)                                                      \
        {                                                                     \
            v4f nx;                                                           \
            if ((c) + 8 < 16)                                                 \
                nx = __builtin_nontemporal_load(&x[idx + ((c) + 8) * Tn]);    \
            __builtin_nontemporal_store(acn_interp4(tbl, buf),                \
                                        &out[idx + (c) * Tn]);                \
            if ((c) + 8 < 16) buf = nx;                                       \
        }
        ACN_STEP(0, b0)  ACN_STEP(1, b1)  ACN_STEP(2, b2)  ACN_STEP(3, b3)
        ACN_STEP(4, b4)  ACN_STEP(5, b5)  ACN_STEP(6, b6)  ACN_STEP(7, b7)
        ACN_STEP(8, b0)  ACN_STEP(9, b1)  ACN_STEP(10, b2) ACN_STEP(11, b3)
        ACN_STEP(12, b4) ACN_STEP(13, b5) ACN_STEP(14, b6) ACN_STEP(15, b7)
#undef ACN_STEP
    } else {                            // generic fallback
        for (int i = idx; i < n4; i += Tn) {
            __builtin_nontemporal_store(acn_interp4(tbl, x[i]), &out[i]);
        }
    }
}

extern "C" void kernel_launch(void* const* d_in, const int* in_sizes, int n_in,
                              void* d_out, int out_size, void* d_ws, size_t ws_size,
                              hipStream_t stream) {
    const float* x        = (const float*)d_in[0];
    const float* mean     = (const float*)d_in[1];
    const float* variance = (const float*)d_in[2];
    const float* prior    = (const float*)d_in[3];
    float* out = (float*)d_out;
    (void)d_ws; (void)ws_size;

    int n4 = out_size / 4;        // 4,194,304 = 16 * (1024*256)
    const int block = 256;
    const int grid  = 1024;       // all blocks resident: 4/CU, 16 waves/CU
    acn_fused<<<grid, block, 0, stream>>>((const v4f*)x, (v4f*)out,
                                          mean, variance, prior, n4);
}

// Round 3
// 113.853 us; speedup vs baseline: 1.0929x; 1.0929x over previous
//
#include <hip/hip_runtime.h>
#include <hip/hip_fp16.h>

#define ACN_EPS   0.001f
#define ACN_LOG2E 1.4426950408889634f
#define ACN_LN2   0.6931471805599453f
#define TBL_N     2048
#define TBL_LO    -8.0f
#define TBL_SCALE 128.0f      // TBL_N / (HI-LO) = 2048/16
#define TBL_OFF   1024.0f     // -TBL_LO * TBL_SCALE
#define TBL_MAX_T 2047.999f

typedef float v4f  __attribute__((ext_vector_type(4)));
typedef unsigned int u32;
typedef u32 v4u __attribute__((ext_vector_type(4)));

// ---------------------------------------------------------------------------
// Per-element interpolation: fma/med3/cvt -> one ds_read_b32 gather ->
// 2x cvt_f32_f16 -> interp fma. Memory-bound.
// ---------------------------------------------------------------------------
__device__ __forceinline__ float acn_interp(const u32* tbl, float xx) {
    float t  = fmaf(xx, TBL_SCALE, TBL_OFF);
    t        = __builtin_amdgcn_fmed3f(t, 0.0f, TBL_MAX_T);
    int   ii = (int)t;
    float f  = t - (float)ii;
    u32 u = tbl[ii];
    __half2 hv = *(const __half2*)&u;
    return fmaf(__high2float(hv), f, __low2float(hv));
}

__device__ __forceinline__ v4f acn_interp4(const u32* tbl, v4f xv) {
    v4f r;
    r.x = acn_interp(tbl, xv.x);
    r.y = acn_interp(tbl, xv.y);
    r.z = acn_interp(tbl, xv.z);
    r.w = acn_interp(tbl, xv.w);
    return r;
}

// ---------------------------------------------------------------------------
// Fused kernel, R1 structure + fixes from R2 post-mortem:
//  - param loads issued FIRST (vmcnt retires in order: params must not queue
//    behind x-prefetch, else the build serializes on prefetch completion)
//  - depth-4 prefetch with PLAIN loads (16 MB chip-wide in flight > 5.8 MB
//    BW*latency product; R2's NT loads + depth-8 regressed)
//  - per-block LDS table build hidden under the in-flight loads
// ---------------------------------------------------------------------------
__global__ __launch_bounds__(256, 4) void acn_fused(
        const v4f* __restrict__ x,
        v4f* __restrict__ out,
        const float* __restrict__ mean,
        const float* __restrict__ variance,
        const float* __restrict__ prior,
        int n4) {
    __shared__ u32 tbl[TBL_N];

    const int Tn  = gridDim.x * blockDim.x;   // 1024*256 = 262144
    const int idx = blockIdx.x * blockDim.x + threadIdx.x;
    const bool fast = (n4 == 16 * Tn);

    // ---- params first: these loads must retire before the build can run,
    // so they go at the head of the vmcnt queue. ----
    float pr[8], mn[8], vrr[8];
#pragma unroll
    for (int k = 0; k < 8; ++k) {
        pr[k]  = prior[k];
        mn[k]  = mean[k];
        vrr[k] = variance[k];
    }

    // Depth-4 prefetch: ~16 MB chip-wide in flight while the table builds.
    v4f b0, b1, b2, b3;
    if (fast) {
        b0 = x[idx];
        b1 = x[idx + 1 * Tn];
        b2 = x[idx + 2 * Tn];
        b3 = x[idx + 3 * Tn];
    }

    // ---- table build (all-intrinsic math) ----
    {
        float e[8];
        float mx = -1e30f;
#pragma unroll
        for (int k = 0; k < 8; ++k) { e[k] = pr[k]; mx = fmaxf(mx, e[k]); }
        float sum = 0.0f;
#pragma unroll
        for (int k = 0; k < 8; ++k) {
            e[k] = __builtin_amdgcn_exp2f((e[k] - mx) * ACN_LOG2E);
            sum += e[k];
        }
        float rs = __builtin_amdgcn_rcpf(sum);

        const float h  = 1.0f / TBL_SCALE;
        const float x0 = TBL_LO + (float)(threadIdx.x * 8) * h;

        float denom[9], S[9];
#pragma unroll
        for (int j = 0; j < 9; ++j) { denom[j] = 0.0f; S[j] = 0.0f; }

#pragma unroll
        for (int k = 0; k < 8; ++k) {
            float pk = e[k] * rs;                                 // softmax(prior)
            // softplus(v) = ln(1 + e^v) = log2(1 + 2^(v*log2e)) * ln2
            float v  = __builtin_amdgcn_logf(1.0f +
                         __builtin_amdgcn_exp2f(vrr[k] * ACN_LOG2E)) * ACN_LN2;
            float ve = v + ACN_EPS;
            float rv  = __builtin_amdgcn_rcpf(v);
            float rve = __builtin_amdgcn_rcpf(ve);
            float mu  = mn[k];
            float s1  = -0.5f * ACN_LOG2E * rv * rv;
            float s2  = -0.5f * ACN_LOG2E * rve * rve;
            float lp  = __builtin_amdgcn_logf(pk);
            float lw  = lp - 0.5f * __builtin_amdgcn_logf(pk + ACN_EPS)
                           - 0.5f * __builtin_amdgcn_logf(ve);
#pragma unroll
            for (int j = 0; j < 9; ++j) {
                float d  = x0 + (float)j * h - mu;
                float d2 = d * d;
                denom[j] += __builtin_amdgcn_exp2f(fmaf(s1, d2, lp));
                S[j] = fmaf(__builtin_amdgcn_exp2f(fmaf(s2, d2, lw)), d, S[j]);
            }
        }

        u32 packed[8];
        float y_prev = S[0] * __builtin_amdgcn_rcpf(denom[0] + ACN_EPS);
#pragma unroll
        for (int j = 0; j < 8; ++j) {
            float y_next = S[j + 1] * __builtin_amdgcn_rcpf(denom[j + 1] + ACN_EPS);
            __half2 hv = __halves2half2(__float2half(y_prev),
                                        __float2half(y_next - y_prev));
            packed[j] = *(const u32*)&hv;
            y_prev = y_next;
        }
        // 8 consecutive dwords per thread -> two b128 writes (one-time cost).
        *(v4u*)&tbl[threadIdx.x * 8]     = *(v4u*)&packed[0];
        *(v4u*)&tbl[threadIdx.x * 8 + 4] = *(v4u*)&packed[4];
    }
    __syncthreads();

    // ---- streaming main loop: depth-4 software pipeline, static regs ----
    if (fast) {
#define ACN_STEP(c, buf)                                                      \
        {                                                                     \
            v4f nx;                                                           \
            if ((c) + 4 < 16) nx = x[idx + ((c) + 4) * Tn];                   \
            __builtin_nontemporal_store(acn_interp4(tbl, buf),                \
                                        &out[idx + (c) * Tn]);                \
            if ((c) + 4 < 16) buf = nx;                                       \
        }
        ACN_STEP(0, b0)  ACN_STEP(1, b1)  ACN_STEP(2, b2)  ACN_STEP(3, b3)
        ACN_STEP(4, b0)  ACN_STEP(5, b1)  ACN_STEP(6, b2)  ACN_STEP(7, b3)
        ACN_STEP(8, b0)  ACN_STEP(9, b1)  ACN_STEP(10, b2) ACN_STEP(11, b3)
        ACN_STEP(12, b0) ACN_STEP(13, b1) ACN_STEP(14, b2) ACN_STEP(15, b3)
#undef ACN_STEP
    } else {                            // generic fallback
        for (int i = idx; i < n4; i += Tn) {
            __builtin_nontemporal_store(acn_interp4(tbl, x[i]), &out[i]);
        }
    }
}

extern "C" void kernel_launch(void* const* d_in, const int* in_sizes, int n_in,
                              void* d_out, int out_size, void* d_ws, size_t ws_size,
                              hipStream_t stream) {
    const float* x        = (const float*)d_in[0];
    const float* mean     = (const float*)d_in[1];
    const float* variance = (const float*)d_in[2];
    const float* prior    = (const float*)d_in[3];
    float* out = (float*)d_out;
    (void)d_ws; (void)ws_size;

    int n4 = out_size / 4;        // 4,194,304 = 16 * (1024*256)
    const int block = 256;
    const int grid  = 1024;       // all blocks resident: 4/CU, 16 waves/CU
    acn_fused<<<grid, block, 0, stream>>>((const v4f*)x, (v4f*)out,
                                          mean, variance, prior, n4);
}